// Round 2
// baseline (234.176 us; speedup 1.0000x reference)
//
#include <hip/hip_runtime.h>

// Problem constants (from reference): B=16, K=8, C=64, L=2048
#define BB 16
#define KK 8
#define CC 64
#define LL 2048

constexpr int CL = CC * LL;              // 131072 elements per batch image
constexpr int QUADS_PER_BATCH = CL / 4;  // 32768 float4-quads per batch
constexpr int NBLOCKS = (BB * QUADS_PER_BATCH) / 256;  // 2048 blocks of 256 threads

// 1 - sigmoid(2.0) = sigmoid(-2.0)
#define SIG_OFF 0.11920292202211755f
#define EPS_U 1e-7f

__device__ __forceinline__ float softplus_f(float x) {
    // stable: max(x,0) + log1p(exp(-|x|))
    return fmaxf(x, 0.f) + log1pf(__expf(-fabsf(x)));
}

__device__ __forceinline__ float get4(const float4& v, int e) {
    switch (e) {
        case 0: return v.x;
        case 1: return v.y;
        case 2: return v.z;
        default: return v.w;
    }
}

__device__ __forceinline__ void set4(float4& v, int e, float f) {
    switch (e) {
        case 0: v.x = f; break;
        case 1: v.y = f; break;
        case 2: v.z = f; break;
        default: v.w = f; break;
    }
}

__global__ void init_sldj_kernel(const float* __restrict__ sldj_in,
                                 float* __restrict__ sldj_out) {
    int i = threadIdx.x;
    if (i < BB) sldj_out[i] = sldj_in[i];
}

__global__ __launch_bounds__(256) void coupling_kernel(
    const float* __restrict__ x,
    const float* __restrict__ a,
    const float* __restrict__ bv,
    const float* __restrict__ pi,
    const float* __restrict__ mu,
    const float* __restrict__ s,
    float* __restrict__ out,
    float* __restrict__ sldj_out) {

    const int idx = blockIdx.x * 256 + threadIdx.x;  // global quad index
    const int b   = idx >> 15;                       // / QUADS_PER_BATCH (32768)
    const int rem = idx & (QUADS_PER_BATCH - 1);
    const int base = b * CL + rem * 4;

    const float4 x4 = *(const float4*)(x + base);
    const float4 a4 = *(const float4*)(a + base);
    const float4 b4 = *(const float4*)(bv + base);

    float4 pi4[KK], mu4[KK], s4[KK];
#pragma unroll
    for (int k = 0; k < KK; ++k) {
        const int kb = (b * KK + k) * CL + rem * 4;
        pi4[k] = *(const float4*)(pi + kb);
        mu4[k] = *(const float4*)(mu + kb);
        s4[k]  = *(const float4*)(s  + kb);
    }

    float contrib = 0.f;
    float4 out4;

#pragma unroll
    for (int e = 0; e < 4; ++e) {
        const float xe = get4(x4, e);
        const float ae = get4(a4, e);
        const float be = get4(b4, e);

        float piv[KK], argc[KK], argp[KK];
#pragma unroll
        for (int k = 0; k < KK; ++k) {
            const float p  = get4(pi4[k], e);
            const float sk = get4(s4[k], e);
            const float z  = (xe - get4(mu4[k], e)) * __expf(-sk);
            const float sp = softplus_f(z);
            piv[k]  = p;
            argc[k] = p + (z - sp);          // p + log_sigmoid(z)
            argp[k] = p + z - sk - 2.f * sp; // p + log_pdf term
        }

        // Three logsumexps over K=8
        float m_pi = piv[0], m_c = argc[0], m_p = argp[0];
#pragma unroll
        for (int k = 1; k < KK; ++k) {
            m_pi = fmaxf(m_pi, piv[k]);
            m_c  = fmaxf(m_c,  argc[k]);
            m_p  = fmaxf(m_p,  argp[k]);
        }
        float s_pi = 0.f, s_c = 0.f, s_p = 0.f;
#pragma unroll
        for (int k = 0; k < KK; ++k) {
            s_pi += __expf(piv[k]  - m_pi);
            s_c  += __expf(argc[k] - m_c);
            s_p  += __expf(argp[k] - m_p);
        }
        const float lse_pi  = m_pi + __logf(s_pi);
        const float log_cdf = (m_c + __logf(s_c)) - lse_pi;
        const float log_pdf = (m_p + __logf(s_p)) - lse_pi;

        float u = __expf(log_cdf);
        u = fminf(fmaxf(u, EPS_U), 1.f - EPS_U);
        const float lu   = __logf(u);
        const float l1mu = log1pf(-u);   // 1-u exact (Sterbenz) inside log1p
        const float y        = lu - l1mu;
        const float ldj_term = -lu - l1mu;

        const float sc = 1.f / (1.f + __expf(-(ae + 2.f))) + SIG_OFF;

        set4(out4, e, (y + be) * sc);
        contrib += log_pdf + ldj_term + __logf(sc);
    }

    *(float4*)(out + base) = out4;

    // ---- block reduction of contrib, one atomicAdd per block ----
    // wave64 shuffle reduce
#pragma unroll
    for (int off = 32; off > 0; off >>= 1)
        contrib += __shfl_down(contrib, off, 64);

    __shared__ float wsum[4];
    const int lane = threadIdx.x & 63;
    const int wid  = threadIdx.x >> 6;
    if (lane == 0) wsum[wid] = contrib;
    __syncthreads();
    if (threadIdx.x == 0) {
        const float t = wsum[0] + wsum[1] + wsum[2] + wsum[3];
        atomicAdd(&sldj_out[b], t);  // block lies entirely within batch b
    }
}

extern "C" void kernel_launch(void* const* d_in, const int* in_sizes, int n_in,
                              void* d_out, int out_size, void* d_ws, size_t ws_size,
                              hipStream_t stream) {
    const float* x    = (const float*)d_in[0];
    const float* a    = (const float*)d_in[1];
    const float* bv   = (const float*)d_in[2];
    const float* pi   = (const float*)d_in[3];
    const float* mu   = (const float*)d_in[4];
    const float* s    = (const float*)d_in[5];
    const float* sldj = (const float*)d_in[6];

    float* out      = (float*)d_out;
    float* sldj_out = out + (size_t)BB * CL;  // outputs concatenated: out, then sldj

    init_sldj_kernel<<<1, 64, 0, stream>>>(sldj, sldj_out);
    coupling_kernel<<<NBLOCKS, 256, 0, stream>>>(x, a, bv, pi, mu, s, out, sldj_out);
}

// Round 3
// 231.877 us; speedup vs baseline: 1.0099x; 1.0099x over previous
//
#include <hip/hip_runtime.h>

// Problem constants: B=16, K=8, C=64, L=2048
#define BB 16
#define KK 8
#define CC 64
#define LL 2048

constexpr int CL = CC * LL;              // 131072 elems per batch
constexpr int QUADS_PER_BATCH = CL / 4;  // 32768
constexpr int NBLOCKS = (BB * QUADS_PER_BATCH) / 256;  // 2048

#define SIG_OFF 0.11920292202211755f     // 1 - sigmoid(2) = sigmoid(-2)
#define LOG_EPS -16.11809565095832f      // logf(1e-7)

__device__ __forceinline__ float frcp(float x) { return __builtin_amdgcn_rcpf(x); }

__device__ __forceinline__ float get4(const float4& v, int e) {
    switch (e) {
        case 0: return v.x;
        case 1: return v.y;
        case 2: return v.z;
        default: return v.w;
    }
}

__device__ __forceinline__ void set4(float4& v, int e, float f) {
    switch (e) {
        case 0: v.x = f; break;
        case 1: v.y = f; break;
        case 2: v.z = f; break;
        default: v.w = f; break;
    }
}

__global__ void init_sldj_kernel(const float* __restrict__ sldj_in,
                                 float* __restrict__ sldj_out) {
    int i = threadIdx.x;
    if (i < BB) sldj_out[i] = sldj_in[i];
}

__global__ __launch_bounds__(256) void coupling_kernel(
    const float* __restrict__ x,
    const float* __restrict__ a,
    const float* __restrict__ bv,
    const float* __restrict__ pi,
    const float* __restrict__ mu,
    const float* __restrict__ s,
    float* __restrict__ out,
    float* __restrict__ sldj_out) {

    const int idx = blockIdx.x * 256 + threadIdx.x;  // global quad index
    const int b   = idx >> 15;                       // / 32768
    const int rem = idx & (QUADS_PER_BATCH - 1);
    const int base = b * CL + rem * 4;

    const float4 x4 = *(const float4*)(x + base);
    const float4 a4 = *(const float4*)(a + base);
    const float4 b4 = *(const float4*)(bv + base);

    // Linear-domain mixture accumulators, per element of the quad:
    //   Spi = sum_k e^{pi_k}
    //   Nc  = sum_k e^{pi_k} * sigmoid(z_k)            -> u  = Nc/Spi
    //   N1  = sum_k e^{pi_k} * (1 - sigmoid(z_k))      -> 1-u = N1/Spi
    //   Np  = sum_k e^{pi_k} * e^{-s_k} * sig*(1-sig)  -> pdf = Np/Spi
    float Spi[4] = {0.f, 0.f, 0.f, 0.f};
    float Nc[4]  = {0.f, 0.f, 0.f, 0.f};
    float N1[4]  = {0.f, 0.f, 0.f, 0.f};
    float Np[4]  = {0.f, 0.f, 0.f, 0.f};

#pragma unroll
    for (int k = 0; k < KK; ++k) {
        const int kb = (b * KK + k) * CL + rem * 4;
        const float4 pi4 = *(const float4*)(pi + kb);
        const float4 mu4 = *(const float4*)(mu + kb);
        const float4 s4  = *(const float4*)(s  + kb);

#pragma unroll
        for (int e = 0; e < 4; ++e) {
            const float p      = get4(pi4, e);
            const float m      = get4(mu4, e);
            const float sk     = get4(s4, e);
            const float invstd = __expf(-sk);
            const float z      = (get4(x4, e) - m) * invstd;

            // stable sigmoid via t = e^{-|z|}
            const float t  = __expf(-fabsf(z));
            const float r  = frcp(1.f + t);
            const float tr = t * r;
            const float sig  = (z >= 0.f) ? r  : tr;
            const float osig = (z >= 0.f) ? tr : r;

            const float ek = __expf(p);  // pi ~ N(0,1): no overflow risk
            Spi[e] += ek;
            Nc[e]  += ek * sig;
            N1[e]  += ek * osig;
            Np[e]  += ek * invstd * sig * osig;
        }
    }

    float contrib = 0.f;
    float4 out4;

#pragma unroll
    for (int e = 0; e < 4; ++e) {
        const float lSpi = __logf(Spi[e]);
        // clip(u, eps, 1-eps) == clamp both logs at log(eps) (to fp32 accuracy)
        const float lu   = fmaxf(__logf(Nc[e]) - lSpi, LOG_EPS);
        const float lomu = fmaxf(__logf(N1[e]) - lSpi, LOG_EPS);
        const float y        = lu - lomu;     // logit
        const float ldj_term = -lu - lomu;
        const float log_pdf  = __logf(Np[e]) - lSpi;

        // scale = sigmoid(a+2) + sigmoid(-2)
        const float ae = get4(a4, e) + 2.f;
        const float t2 = __expf(-fabsf(ae));
        const float r2 = frcp(1.f + t2);
        const float sc = ((ae >= 0.f) ? r2 : t2 * r2) + SIG_OFF;

        set4(out4, e, (y + get4(b4, e)) * sc);
        contrib += log_pdf + ldj_term + __logf(sc);
    }

    *(float4*)(out + base) = out4;

    // ---- block reduction, one atomicAdd per block (block is within batch b) ----
#pragma unroll
    for (int off = 32; off > 0; off >>= 1)
        contrib += __shfl_down(contrib, off, 64);

    __shared__ float wsum[4];
    const int lane = threadIdx.x & 63;
    const int wid  = threadIdx.x >> 6;
    if (lane == 0) wsum[wid] = contrib;
    __syncthreads();
    if (threadIdx.x == 0) {
        atomicAdd(&sldj_out[b], wsum[0] + wsum[1] + wsum[2] + wsum[3]);
    }
}

extern "C" void kernel_launch(void* const* d_in, const int* in_sizes, int n_in,
                              void* d_out, int out_size, void* d_ws, size_t ws_size,
                              hipStream_t stream) {
    const float* x    = (const float*)d_in[0];
    const float* a    = (const float*)d_in[1];
    const float* bv   = (const float*)d_in[2];
    const float* pi   = (const float*)d_in[3];
    const float* mu   = (const float*)d_in[4];
    const float* s    = (const float*)d_in[5];
    const float* sldj = (const float*)d_in[6];

    float* out      = (float*)d_out;
    float* sldj_out = out + (size_t)BB * CL;  // outputs concat: out, then sldj

    init_sldj_kernel<<<1, 64, 0, stream>>>(sldj, sldj_out);
    coupling_kernel<<<NBLOCKS, 256, 0, stream>>>(x, a, bv, pi, mu, s, out, sldj_out);
}

// Round 4
// 223.070 us; speedup vs baseline: 1.0498x; 1.0395x over previous
//
#include <hip/hip_runtime.h>

// Problem constants: B=16, K=8, C=64, L=2048
#define BB 16
#define KK 8
#define CC 64
#define LL 2048

constexpr int CL = CC * LL;              // 131072 elems per batch
constexpr int QUADS_PER_BATCH = CL / 4;  // 32768
constexpr int NBLOCKS = (BB * QUADS_PER_BATCH) / 256;  // 2048

#define SIG_OFF 0.11920292202211755f     // 1 - sigmoid(2) = sigmoid(-2)
#define LOG_EPS -16.11809565095832f      // logf(1e-7)

__device__ __forceinline__ float frcp(float x) { return __builtin_amdgcn_rcpf(x); }

__device__ __forceinline__ float get4(const float4& v, int e) {
    switch (e) {
        case 0: return v.x;
        case 1: return v.y;
        case 2: return v.z;
        default: return v.w;
    }
}

__device__ __forceinline__ void set4(float4& v, int e, float f) {
    switch (e) {
        case 0: v.x = f; break;
        case 1: v.y = f; break;
        case 2: v.z = f; break;
        default: v.w = f; break;
    }
}

__global__ void init_sldj_kernel(const float* __restrict__ sldj_in,
                                 float* __restrict__ sldj_out) {
    int i = threadIdx.x;
    if (i < BB) sldj_out[i] = sldj_in[i];
}

// __launch_bounds__(256, 2): allow up to ~256 VGPRs so the full 27-float4
// preload (108 regs of payload) stays in registers instead of being re-sunk
// into the k-loop (R2/R3 had VGPR=80/36 -> only ~3 loads in flight -> latency
// bound at ~2 TB/s effective).
__global__ __launch_bounds__(256, 2) void coupling_kernel(
    const float* __restrict__ x,
    const float* __restrict__ a,
    const float* __restrict__ bv,
    const float* __restrict__ pi,
    const float* __restrict__ mu,
    const float* __restrict__ s,
    float* __restrict__ out,
    float* __restrict__ sldj_out) {

    const int idx = blockIdx.x * 256 + threadIdx.x;  // global quad index
    const int b   = idx >> 15;                       // / 32768
    const int rem = idx & (QUADS_PER_BATCH - 1);
    const int base = b * CL + rem * 4;

    // ---- Phase 1: issue ALL loads back-to-back (27 float4 = 27 KB/wave MLP) ----
    const float4 x4 = *(const float4*)(x + base);
    const float4 a4 = *(const float4*)(a + base);
    const float4 b4 = *(const float4*)(bv + base);

    float4 pi4[KK], mu4[KK], s4[KK];
#pragma unroll
    for (int k = 0; k < KK; ++k) {
        const int kb = (b * KK + k) * CL + rem * 4;
        pi4[k] = *(const float4*)(pi + kb);
        mu4[k] = *(const float4*)(mu + kb);
        s4[k]  = *(const float4*)(s  + kb);
    }
    // Fence: keep the load burst above, all compute below.
    __builtin_amdgcn_sched_barrier(0);

    // ---- Phase 2: linear-domain mixture math (no per-k transcendental LSEs) ----
    //   Spi = sum_k e^{pi_k}
    //   Nc  = sum_k e^{pi_k} * sigmoid(z_k)            -> u   = Nc/Spi
    //   N1  = sum_k e^{pi_k} * (1 - sigmoid(z_k))      -> 1-u = N1/Spi
    //   Np  = sum_k e^{pi_k} * e^{-s_k} * sig*(1-sig)  -> pdf = Np/Spi
    float Spi[4] = {0.f, 0.f, 0.f, 0.f};
    float Nc[4]  = {0.f, 0.f, 0.f, 0.f};
    float N1[4]  = {0.f, 0.f, 0.f, 0.f};
    float Np[4]  = {0.f, 0.f, 0.f, 0.f};

#pragma unroll
    for (int k = 0; k < KK; ++k) {
#pragma unroll
        for (int e = 0; e < 4; ++e) {
            const float p      = get4(pi4[k], e);
            const float m      = get4(mu4[k], e);
            const float sk     = get4(s4[k], e);
            const float invstd = __expf(-sk);
            const float z      = (get4(x4, e) - m) * invstd;

            // stable sigmoid via t = e^{-|z|}
            const float t  = __expf(-fabsf(z));
            const float r  = frcp(1.f + t);
            const float tr = t * r;
            const float sig  = (z >= 0.f) ? r  : tr;
            const float osig = (z >= 0.f) ? tr : r;

            const float ek = __expf(p);
            Spi[e] += ek;
            Nc[e]  += ek * sig;
            N1[e]  += ek * osig;
            Np[e]  += ek * invstd * sig * osig;
        }
    }

    float contrib = 0.f;
    float4 out4;

#pragma unroll
    for (int e = 0; e < 4; ++e) {
        const float lSpi = __logf(Spi[e]);
        const float lu   = fmaxf(__logf(Nc[e]) - lSpi, LOG_EPS);
        const float lomu = fmaxf(__logf(N1[e]) - lSpi, LOG_EPS);
        const float y        = lu - lomu;     // logit
        const float ldj_term = -lu - lomu;
        const float log_pdf  = __logf(Np[e]) - lSpi;

        // scale = sigmoid(a+2) + sigmoid(-2)
        const float ae = get4(a4, e) + 2.f;
        const float t2 = __expf(-fabsf(ae));
        const float r2 = frcp(1.f + t2);
        const float sc = ((ae >= 0.f) ? r2 : t2 * r2) + SIG_OFF;

        set4(out4, e, (y + get4(b4, e)) * sc);
        contrib += log_pdf + ldj_term + __logf(sc);
    }

    *(float4*)(out + base) = out4;

    // ---- block reduction, one atomicAdd per block (block is within batch b) ----
#pragma unroll
    for (int off = 32; off > 0; off >>= 1)
        contrib += __shfl_down(contrib, off, 64);

    __shared__ float wsum[4];
    const int lane = threadIdx.x & 63;
    const int wid  = threadIdx.x >> 6;
    if (lane == 0) wsum[wid] = contrib;
    __syncthreads();
    if (threadIdx.x == 0) {
        atomicAdd(&sldj_out[b], wsum[0] + wsum[1] + wsum[2] + wsum[3]);
    }
}

extern "C" void kernel_launch(void* const* d_in, const int* in_sizes, int n_in,
                              void* d_out, int out_size, void* d_ws, size_t ws_size,
                              hipStream_t stream) {
    const float* x    = (const float*)d_in[0];
    const float* a    = (const float*)d_in[1];
    const float* bv   = (const float*)d_in[2];
    const float* pi   = (const float*)d_in[3];
    const float* mu   = (const float*)d_in[4];
    const float* s    = (const float*)d_in[5];
    const float* sldj = (const float*)d_in[6];

    float* out      = (float*)d_out;
    float* sldj_out = out + (size_t)BB * CL;  // outputs concat: out, then sldj

    init_sldj_kernel<<<1, 64, 0, stream>>>(sldj, sldj_out);
    coupling_kernel<<<NBLOCKS, 256, 0, stream>>>(x, a, bv, pi, mu, s, out, sldj_out);
}